// Round 1
// baseline (1325.113 us; speedup 1.0000x reference)
//
#include <hip/hip_runtime.h>

#define NNODES 50000
#define NEDGES 640000
#define NF 128
#define EF 128
#define UF 64
#define HID 256
#define ZK 448  // NF + HID + UF

typedef float floatx4 __attribute__((ext_vector_type(4)));
typedef __bf16 bf16x8 __attribute__((ext_vector_type(8)));

__device__ __forceinline__ unsigned short f2bf(float f) {
    unsigned int u = __float_as_uint(f);
    u += 0x7fffu + ((u >> 16) & 1u);   // RNE
    return (unsigned short)(u >> 16);
}

// wt[n*K + k] = w[k*N + n]  (K-major bf16 copy for MFMA B-operand loads)
__global__ void kconv_t(const float* __restrict__ w, unsigned short* __restrict__ wt,
                        int K, int N) {
    int i = blockIdx.x * 256 + threadIdx.x;
    if (i >= K * N) return;
    int n = i / K, k = i - n * K;
    wt[i] = f2bf(w[(size_t)k * N + n]);
}

__global__ void kcount(const int* __restrict__ eidx, int* __restrict__ cnt) {
    int i = blockIdx.x * 256 + threadIdx.x;
    if (i < NEDGES) atomicAdd(&cnt[eidx[NEDGES + i]], 1);
}

__global__ void kinv(const int* __restrict__ cnt, float* __restrict__ inv) {
    int i = blockIdx.x * 256 + threadIdx.x;
    if (i < NNODES) {
        int c = cnt[i];
        inv[i] = 1.0f / (float)(c > 1 ? c : 1);
    }
}

// LDS row stride for 256-wide bf16 tiles: 264*2=528 B -> 16B-aligned, banks step 4 (2-way, free)
#define EST 264

__global__ __launch_bounds__(256)
void kedge(const float* __restrict__ x, const int* __restrict__ eidx,
           const float* __restrict__ ea,
           const unsigned short* __restrict__ W1t, const float* __restrict__ b1,
           const unsigned short* __restrict__ W2t, const float* __restrict__ b2,
           float* __restrict__ agg) {
    __shared__ unsigned short sA[64 * EST];
    __shared__ int sRow[64], sCol[64];
    const int tid = threadIdx.x;
    const int e0 = blockIdx.x * 64;

    if (tid < 64) {
        sRow[tid] = eidx[e0 + tid];
        sCol[tid] = eidx[NEDGES + e0 + tid];
    }
    __syncthreads();

    // stage A = [x[row] || ea[e]] -> bf16 LDS, 64 rows x 256 cols
    for (int i = 0; i < 16; ++i) {
        int lin = (i << 10) + (tid << 2);
        int r = lin >> 8, c = lin & 255;
        const float* src = (c < NF) ? (x + (size_t)sRow[r] * NF + c)
                                    : (ea + (size_t)(e0 + r) * EF + (c - NF));
        float4 v = *(const float4*)src;
        unsigned lo = (unsigned)f2bf(v.x) | ((unsigned)f2bf(v.y) << 16);
        unsigned hi = (unsigned)f2bf(v.z) | ((unsigned)f2bf(v.w) << 16);
        *(uint2*)&sA[r * EST + c] = make_uint2(lo, hi);
    }
    __syncthreads();

    const int lane = tid & 63, wave = tid >> 6;
    const int l16 = lane & 15, quad = lane >> 4;
    const int nbase = wave * 64;
    const floatx4 fz = {0.f, 0.f, 0.f, 0.f};

    // ---- layer 1: h1 = relu(A @ W1 + b1), K=256, this wave covers cols [nbase, nbase+64)
    floatx4 acc[4][4];
    #pragma unroll
    for (int mi = 0; mi < 4; ++mi)
        #pragma unroll
        for (int ni = 0; ni < 4; ++ni) acc[mi][ni] = fz;

    #pragma unroll 2
    for (int ks = 0; ks < 8; ++ks) {
        const int k0 = ks * 32 + quad * 8;
        bf16x8 a[4], b[4];
        #pragma unroll
        for (int mi = 0; mi < 4; ++mi)
            a[mi] = *(const bf16x8*)&sA[(mi * 16 + l16) * EST + k0];
        #pragma unroll
        for (int ni = 0; ni < 4; ++ni)
            b[ni] = *(const bf16x8*)&W1t[(size_t)(nbase + ni * 16 + l16) * HID + k0];
        #pragma unroll
        for (int mi = 0; mi < 4; ++mi)
            #pragma unroll
            for (int ni = 0; ni < 4; ++ni)
                acc[mi][ni] = __builtin_amdgcn_mfma_f32_16x16x32_bf16(a[mi], b[ni], acc[mi][ni], 0, 0, 0);
    }
    __syncthreads();  // all waves done reading sA

    // write h1 (bf16) back into sA; D layout: col=lane&15(+16*ni), row=quad*4+reg(+16*mi)
    #pragma unroll
    for (int ni = 0; ni < 4; ++ni) {
        const int n = nbase + ni * 16 + l16;
        const float bias = b1[n];
        #pragma unroll
        for (int mi = 0; mi < 4; ++mi)
            #pragma unroll
            for (int r = 0; r < 4; ++r) {
                const int row = mi * 16 + quad * 4 + r;
                sA[row * EST + n] = f2bf(fmaxf(acc[mi][ni][r] + bias, 0.f));
            }
    }
    __syncthreads();

    // ---- layer 2: h = h1 @ W2 + b2, then scatter-add to agg[col]
    floatx4 acc2[4][4];
    #pragma unroll
    for (int mi = 0; mi < 4; ++mi)
        #pragma unroll
        for (int ni = 0; ni < 4; ++ni) acc2[mi][ni] = fz;

    #pragma unroll 2
    for (int ks = 0; ks < 8; ++ks) {
        const int k0 = ks * 32 + quad * 8;
        bf16x8 a[4], b[4];
        #pragma unroll
        for (int mi = 0; mi < 4; ++mi)
            a[mi] = *(const bf16x8*)&sA[(mi * 16 + l16) * EST + k0];
        #pragma unroll
        for (int ni = 0; ni < 4; ++ni)
            b[ni] = *(const bf16x8*)&W2t[(size_t)(nbase + ni * 16 + l16) * HID + k0];
        #pragma unroll
        for (int mi = 0; mi < 4; ++mi)
            #pragma unroll
            for (int ni = 0; ni < 4; ++ni)
                acc2[mi][ni] = __builtin_amdgcn_mfma_f32_16x16x32_bf16(a[mi], b[ni], acc2[mi][ni], 0, 0, 0);
    }

    #pragma unroll
    for (int ni = 0; ni < 4; ++ni) {
        const int n = nbase + ni * 16 + l16;
        const float bias = b2[n];
        #pragma unroll
        for (int mi = 0; mi < 4; ++mi)
            #pragma unroll
            for (int r = 0; r < 4; ++r) {
                const int row = mi * 16 + quad * 4 + r;
                const int node = sCol[row];
                unsafeAtomicAdd(&agg[(size_t)node * HID + n], acc2[mi][ni][r] + bias);
            }
    }
}

// LDS row stride for 448-wide tiles: 456*2=912 B -> 16B-aligned, banks step 4
#define ZST 456

__global__ __launch_bounds__(256)
void knode(const float* __restrict__ x, const float* __restrict__ agg,
           const float* __restrict__ inv, const float* __restrict__ u,
           const int* __restrict__ batch,
           const unsigned short* __restrict__ W3t, const float* __restrict__ b3,
           const unsigned short* __restrict__ W4t, const float* __restrict__ b4,
           float* __restrict__ out) {
    __shared__ unsigned short sZ[64 * ZST];
    const int tid = threadIdx.x;
    const int n0 = blockIdx.x * 64;

    // stage z = [x || agg*inv || u[batch]] -> bf16 LDS, 64 rows x 448 cols (4 threads/row)
    {
        const int r = tid >> 2, q = tid & 3;
        const int nc = min(n0 + r, NNODES - 1);
        const float invv = inv[nc];
        const int bg = batch[nc];
        for (int j = 0; j < 28; ++j) {
            const int c = q * 112 + (j << 2);
            float4 v;
            if (c < NF) {
                v = *(const float4*)(x + (size_t)nc * NF + c);
            } else if (c < NF + HID) {
                v = *(const float4*)(agg + (size_t)nc * HID + (c - NF));
                v.x *= invv; v.y *= invv; v.z *= invv; v.w *= invv;
            } else {
                v = *(const float4*)(u + (size_t)bg * UF + (c - NF - HID));
            }
            unsigned lo = (unsigned)f2bf(v.x) | ((unsigned)f2bf(v.y) << 16);
            unsigned hi = (unsigned)f2bf(v.z) | ((unsigned)f2bf(v.w) << 16);
            *(uint2*)&sZ[r * ZST + c] = make_uint2(lo, hi);
        }
    }
    __syncthreads();

    const int lane = tid & 63, wave = tid >> 6;
    const int l16 = lane & 15, quad = lane >> 4;
    const floatx4 fz = {0.f, 0.f, 0.f, 0.f};

    // ---- layer 1: t = relu(z @ W3 + b3), K=448, N=256
    {
        const int nbase = wave * 64;
        floatx4 acc[4][4];
        #pragma unroll
        for (int mi = 0; mi < 4; ++mi)
            #pragma unroll
            for (int ni = 0; ni < 4; ++ni) acc[mi][ni] = fz;

        #pragma unroll 2
        for (int ks = 0; ks < 14; ++ks) {
            const int k0 = ks * 32 + quad * 8;
            bf16x8 a[4], b[4];
            #pragma unroll
            for (int mi = 0; mi < 4; ++mi)
                a[mi] = *(const bf16x8*)&sZ[(mi * 16 + l16) * ZST + k0];
            #pragma unroll
            for (int ni = 0; ni < 4; ++ni)
                b[ni] = *(const bf16x8*)&W3t[(size_t)(nbase + ni * 16 + l16) * ZK + k0];
            #pragma unroll
            for (int mi = 0; mi < 4; ++mi)
                #pragma unroll
                for (int ni = 0; ni < 4; ++ni)
                    acc[mi][ni] = __builtin_amdgcn_mfma_f32_16x16x32_bf16(a[mi], b[ni], acc[mi][ni], 0, 0, 0);
        }
        __syncthreads();
        #pragma unroll
        for (int ni = 0; ni < 4; ++ni) {
            const int n = nbase + ni * 16 + l16;
            const float bias = b3[n];
            #pragma unroll
            for (int mi = 0; mi < 4; ++mi)
                #pragma unroll
                for (int r = 0; r < 4; ++r) {
                    const int row = mi * 16 + quad * 4 + r;
                    sZ[row * ZST + n] = f2bf(fmaxf(acc[mi][ni][r] + bias, 0.f));
                }
        }
        __syncthreads();
    }

    // ---- layer 2: out = t @ W4 + b4, K=256, N=128 (each wave covers 32 cols)
    {
        const int nbase = wave * 32;
        floatx4 acc[4][2];
        #pragma unroll
        for (int mi = 0; mi < 4; ++mi)
            #pragma unroll
            for (int ni = 0; ni < 2; ++ni) acc[mi][ni] = fz;

        #pragma unroll 2
        for (int ks = 0; ks < 8; ++ks) {
            const int k0 = ks * 32 + quad * 8;
            bf16x8 a[4], b[2];
            #pragma unroll
            for (int mi = 0; mi < 4; ++mi)
                a[mi] = *(const bf16x8*)&sZ[(mi * 16 + l16) * ZST + k0];
            #pragma unroll
            for (int ni = 0; ni < 2; ++ni)
                b[ni] = *(const bf16x8*)&W4t[(size_t)(nbase + ni * 16 + l16) * HID + k0];
            #pragma unroll
            for (int mi = 0; mi < 4; ++mi)
                #pragma unroll
                for (int ni = 0; ni < 2; ++ni)
                    acc[mi][ni] = __builtin_amdgcn_mfma_f32_16x16x32_bf16(a[mi], b[ni], acc[mi][ni], 0, 0, 0);
        }
        #pragma unroll
        for (int ni = 0; ni < 2; ++ni) {
            const int feat = nbase + ni * 16 + l16;
            const float bias = b4[feat];
            #pragma unroll
            for (int mi = 0; mi < 4; ++mi)
                #pragma unroll
                for (int r = 0; r < 4; ++r) {
                    const int row = mi * 16 + quad * 4 + r;
                    const int n = n0 + row;
                    if (n < NNODES)
                        out[(size_t)n * NF + feat] = acc[mi][ni][r] + bias;
                }
        }
    }
}

extern "C" void kernel_launch(void* const* d_in, const int* in_sizes, int n_in,
                              void* d_out, int out_size, void* d_ws, size_t ws_size,
                              hipStream_t stream) {
    const float* x   = (const float*)d_in[0];
    const int*   ei  = (const int*)d_in[1];
    const float* ea  = (const float*)d_in[2];
    const float* u   = (const float*)d_in[3];
    const int*   bat = (const int*)d_in[4];
    const float* W1  = (const float*)d_in[5];
    const float* b1  = (const float*)d_in[6];
    const float* W2  = (const float*)d_in[7];
    const float* b2  = (const float*)d_in[8];
    const float* W3  = (const float*)d_in[9];
    const float* b3  = (const float*)d_in[10];
    const float* W4  = (const float*)d_in[11];
    const float* b4  = (const float*)d_in[12];
    float* out = (float*)d_out;

    char* p = (char*)d_ws;
    float* agg = (float*)p;                   p += (size_t)NNODES * HID * 4;
    int* cnt   = (int*)p;                     p += (size_t)NNODES * 4;
    float* inv = (float*)p;                   p += (size_t)NNODES * 4;
    unsigned short* W1t = (unsigned short*)p; p += (size_t)HID * HID * 2;
    unsigned short* W2t = (unsigned short*)p; p += (size_t)HID * HID * 2;
    unsigned short* W3t = (unsigned short*)p; p += (size_t)ZK * HID * 2;
    unsigned short* W4t = (unsigned short*)p; p += (size_t)HID * NF * 2;

    hipMemsetAsync(agg, 0, (size_t)NNODES * HID * 4, stream);
    hipMemsetAsync(cnt, 0, (size_t)NNODES * 4, stream);

    kconv_t<<<(HID * HID + 255) / 256, 256, 0, stream>>>(W1, W1t, HID, HID);
    kconv_t<<<(HID * HID + 255) / 256, 256, 0, stream>>>(W2, W2t, HID, HID);
    kconv_t<<<(ZK * HID + 255) / 256, 256, 0, stream>>>(W3, W3t, ZK, HID);
    kconv_t<<<(HID * NF + 255) / 256, 256, 0, stream>>>(W4, W4t, HID, NF);
    kcount<<<(NEDGES + 255) / 256, 256, 0, stream>>>(ei, cnt);
    kinv<<<(NNODES + 255) / 256, 256, 0, stream>>>(cnt, inv);

    kedge<<<NEDGES / 64, 256, 0, stream>>>(x, ei, ea, W1t, b1, W2t, b2, agg);
    knode<<<(NNODES + 63) / 64, 256, 0, stream>>>(x, agg, inv, u, bat, W3t, b3, W4t, b4, out);
}

// Round 2
// 1242.222 us; speedup vs baseline: 1.0667x; 1.0667x over previous
//
#include <hip/hip_runtime.h>

#define NNODES 50000
#define NEDGES 640000
#define NF 128
#define EF 128
#define UF 64
#define HID 256
#define ZK 448  // NF + HID + UF
#define NSCANB 196  // ceil(NNODES/256)

typedef float floatx4 __attribute__((ext_vector_type(4)));
typedef __bf16 bf16x8 __attribute__((ext_vector_type(8)));

__device__ __forceinline__ unsigned short f2bf(float f) {
    unsigned int u = __float_as_uint(f);
    u += 0x7fffu + ((u >> 16) & 1u);   // RNE
    return (unsigned short)(u >> 16);
}

// wt[n*K + k] = w[k*N + n]  (K-major bf16 copy for MFMA B-operand loads)
__global__ void kconv_t(const float* __restrict__ w, unsigned short* __restrict__ wt,
                        int K, int N) {
    int i = blockIdx.x * 256 + threadIdx.x;
    if (i >= K * N) return;
    int n = i / K, k = i - n * K;
    wt[i] = f2bf(w[(size_t)k * N + n]);
}

__global__ void kcount(const int* __restrict__ eidx, int* __restrict__ cnt) {
    int i = blockIdx.x * 256 + threadIdx.x;
    if (i < NEDGES) atomicAdd(&cnt[eidx[NEDGES + i]], 1);
}

// per-block exclusive scan of cnt -> excl, block totals -> btot
__global__ void kscan1(const int* __restrict__ cnt, int* __restrict__ excl,
                       int* __restrict__ btot) {
    __shared__ int s[256];
    const int t = threadIdx.x, i = blockIdx.x * 256 + t;
    int v = (i < NNODES) ? cnt[i] : 0;
    s[t] = v;
    __syncthreads();
    for (int off = 1; off < 256; off <<= 1) {
        int add = (t >= off) ? s[t - off] : 0;
        __syncthreads();
        s[t] += add;
        __syncthreads();
    }
    if (i < NNODES) excl[i] = s[t] - v;
    if (t == 255) btot[blockIdx.x] = s[255];
}

// single-block exclusive scan of btot (NSCANB <= 256)
__global__ void kscan2(int* __restrict__ btot) {
    __shared__ int s[256];
    const int t = threadIdx.x;
    int v = (t < NSCANB) ? btot[t] : 0;
    s[t] = v;
    __syncthreads();
    for (int off = 1; off < 256; off <<= 1) {
        int add = (t >= off) ? s[t - off] : 0;
        __syncthreads();
        s[t] += add;
        __syncthreads();
    }
    if (t < NSCANB) btot[t] = s[t] - v;
}

// head[i] = global exclusive prefix = excl[i] + btot[blk];  inv = 1/max(cnt,1)
__global__ void kstart(const int* __restrict__ cnt, const int* __restrict__ excl,
                       const int* __restrict__ btot, int* __restrict__ head,
                       float* __restrict__ inv) {
    int i = blockIdx.x * 256 + threadIdx.x;
    if (i >= NNODES) return;
    head[i] = excl[i] + btot[blockIdx.x];
    int c = cnt[i];
    inv[i] = 1.0f / (float)(c > 1 ? c : 1);
}

// counting-sort scatter: order[] = edge ids sorted by dest, sdest[] = that dest
__global__ void kscatter(const int* __restrict__ eidx, int* __restrict__ head,
                         int* __restrict__ order, int* __restrict__ sdest) {
    int e = blockIdx.x * 256 + threadIdx.x;
    if (e < NEDGES) {
        int d = eidx[NEDGES + e];
        int p = atomicAdd(&head[d], 1);
        order[p] = e;
        sdest[p] = d;
    }
}

// LDS row stride for 256-wide bf16 tiles: 264*2=528 B -> 16B-aligned, banks step 4 (2-way, free)
#define EST 264

__global__ __launch_bounds__(256)
void kedge(const float* __restrict__ x, const int* __restrict__ eidx,
           const float* __restrict__ ea,
           const int* __restrict__ order, const int* __restrict__ sdest,
           const unsigned short* __restrict__ W1t, const float* __restrict__ b1,
           const unsigned short* __restrict__ W2t, const float* __restrict__ b2,
           float* __restrict__ agg) {
    __shared__ unsigned short sA[64 * EST];
    __shared__ int sOrd[64], sRow[64], sCol[64];
    const int tid = threadIdx.x;
    // XCD swizzle: blocks bid%8==x cover contiguous sorted-edge range x*1250.. ->
    // each XCD's L2 sees a distinct, mostly-private slice of agg.
    const int vb = (blockIdx.x & 7) * 1250 + (blockIdx.x >> 3);
    const int e0 = vb * 64;

    if (tid < 64) {
        int e = order[e0 + tid];
        sOrd[tid] = e;
        sRow[tid] = eidx[e];
        sCol[tid] = sdest[e0 + tid];
    }
    __syncthreads();

    // stage A = [x[row] || ea[e]] -> bf16 LDS, 64 rows x 256 cols
    for (int i = 0; i < 16; ++i) {
        int lin = (i << 10) + (tid << 2);
        int r = lin >> 8, c = lin & 255;
        const float* src = (c < NF) ? (x + (size_t)sRow[r] * NF + c)
                                    : (ea + (size_t)sOrd[r] * EF + (c - NF));
        float4 v = *(const float4*)src;
        unsigned lo = (unsigned)f2bf(v.x) | ((unsigned)f2bf(v.y) << 16);
        unsigned hi = (unsigned)f2bf(v.z) | ((unsigned)f2bf(v.w) << 16);
        *(uint2*)&sA[r * EST + c] = make_uint2(lo, hi);
    }
    __syncthreads();

    const int lane = tid & 63, wave = tid >> 6;
    const int l16 = lane & 15, quad = lane >> 4;
    const int nbase = wave * 64;
    const floatx4 fz = {0.f, 0.f, 0.f, 0.f};

    // ---- layer 1: h1 = relu(A @ W1 + b1), K=256, this wave covers cols [nbase, nbase+64)
    floatx4 acc[4][4];
    #pragma unroll
    for (int mi = 0; mi < 4; ++mi)
        #pragma unroll
        for (int ni = 0; ni < 4; ++ni) acc[mi][ni] = fz;

    #pragma unroll 2
    for (int ks = 0; ks < 8; ++ks) {
        const int k0 = ks * 32 + quad * 8;
        bf16x8 a[4], b[4];
        #pragma unroll
        for (int mi = 0; mi < 4; ++mi)
            a[mi] = *(const bf16x8*)&sA[(mi * 16 + l16) * EST + k0];
        #pragma unroll
        for (int ni = 0; ni < 4; ++ni)
            b[ni] = *(const bf16x8*)&W1t[(size_t)(nbase + ni * 16 + l16) * HID + k0];
        #pragma unroll
        for (int mi = 0; mi < 4; ++mi)
            #pragma unroll
            for (int ni = 0; ni < 4; ++ni)
                acc[mi][ni] = __builtin_amdgcn_mfma_f32_16x16x32_bf16(a[mi], b[ni], acc[mi][ni], 0, 0, 0);
    }
    __syncthreads();  // all waves done reading sA

    // write h1 (bf16) back into sA; D layout: col=lane&15(+16*ni), row=quad*4+reg(+16*mi)
    #pragma unroll
    for (int ni = 0; ni < 4; ++ni) {
        const int n = nbase + ni * 16 + l16;
        const float bias = b1[n];
        #pragma unroll
        for (int mi = 0; mi < 4; ++mi)
            #pragma unroll
            for (int r = 0; r < 4; ++r) {
                const int row = mi * 16 + quad * 4 + r;
                sA[row * EST + n] = f2bf(fmaxf(acc[mi][ni][r] + bias, 0.f));
            }
    }
    __syncthreads();

    // ---- layer 2: h = h1 @ W2 + b2, then scatter-add to agg[col]
    floatx4 acc2[4][4];
    #pragma unroll
    for (int mi = 0; mi < 4; ++mi)
        #pragma unroll
        for (int ni = 0; ni < 4; ++ni) acc2[mi][ni] = fz;

    #pragma unroll 2
    for (int ks = 0; ks < 8; ++ks) {
        const int k0 = ks * 32 + quad * 8;
        bf16x8 a[4], b[4];
        #pragma unroll
        for (int mi = 0; mi < 4; ++mi)
            a[mi] = *(const bf16x8*)&sA[(mi * 16 + l16) * EST + k0];
        #pragma unroll
        for (int ni = 0; ni < 4; ++ni)
            b[ni] = *(const bf16x8*)&W2t[(size_t)(nbase + ni * 16 + l16) * HID + k0];
        #pragma unroll
        for (int mi = 0; mi < 4; ++mi)
            #pragma unroll
            for (int ni = 0; ni < 4; ++ni)
                acc2[mi][ni] = __builtin_amdgcn_mfma_f32_16x16x32_bf16(a[mi], b[ni], acc2[mi][ni], 0, 0, 0);
    }

    // epilogue: rows are dest-sorted; each (mi,quad) owns 4 CONSECUTIVE sorted
    // rows -> merge equal-dest runs in-register before the atomic (~4x fewer).
    #pragma unroll
    for (int ni = 0; ni < 4; ++ni) {
        const int n = nbase + ni * 16 + l16;
        const float bias = b2[n];
        #pragma unroll
        for (int mi = 0; mi < 4; ++mi) {
            const int rbase = mi * 16 + quad * 4;
            int d0 = sCol[rbase];
            float s = acc2[mi][ni][0] + bias;
            #pragma unroll
            for (int r = 1; r < 4; ++r) {
                const int d = sCol[rbase + r];
                const float v = acc2[mi][ni][r] + bias;
                if (d == d0) {
                    s += v;
                } else {
                    unsafeAtomicAdd(&agg[(size_t)d0 * HID + n], s);
                    d0 = d; s = v;
                }
            }
            unsafeAtomicAdd(&agg[(size_t)d0 * HID + n], s);
        }
    }
}

// LDS row stride for 448-wide tiles: 456*2=912 B -> 16B-aligned, banks step 4
#define ZST 456

__global__ __launch_bounds__(256)
void knode(const float* __restrict__ x, const float* __restrict__ agg,
           const float* __restrict__ inv, const float* __restrict__ u,
           const int* __restrict__ batch,
           const unsigned short* __restrict__ W3t, const float* __restrict__ b3,
           const unsigned short* __restrict__ W4t, const float* __restrict__ b4,
           float* __restrict__ out) {
    __shared__ unsigned short sZ[64 * ZST];
    const int tid = threadIdx.x;
    const int n0 = blockIdx.x * 64;

    // stage z = [x || agg*inv || u[batch]] -> bf16 LDS, 64 rows x 448 cols (4 threads/row)
    {
        const int r = tid >> 2, q = tid & 3;
        const int nc = min(n0 + r, NNODES - 1);
        const float invv = inv[nc];
        const int bg = batch[nc];
        for (int j = 0; j < 28; ++j) {
            const int c = q * 112 + (j << 2);
            float4 v;
            if (c < NF) {
                v = *(const float4*)(x + (size_t)nc * NF + c);
            } else if (c < NF + HID) {
                v = *(const float4*)(agg + (size_t)nc * HID + (c - NF));
                v.x *= invv; v.y *= invv; v.z *= invv; v.w *= invv;
            } else {
                v = *(const float4*)(u + (size_t)bg * UF + (c - NF - HID));
            }
            unsigned lo = (unsigned)f2bf(v.x) | ((unsigned)f2bf(v.y) << 16);
            unsigned hi = (unsigned)f2bf(v.z) | ((unsigned)f2bf(v.w) << 16);
            *(uint2*)&sZ[r * ZST + c] = make_uint2(lo, hi);
        }
    }
    __syncthreads();

    const int lane = tid & 63, wave = tid >> 6;
    const int l16 = lane & 15, quad = lane >> 4;
    const floatx4 fz = {0.f, 0.f, 0.f, 0.f};

    // ---- layer 1: t = relu(z @ W3 + b3), K=448, N=256
    {
        const int nbase = wave * 64;
        floatx4 acc[4][4];
        #pragma unroll
        for (int mi = 0; mi < 4; ++mi)
            #pragma unroll
            for (int ni = 0; ni < 4; ++ni) acc[mi][ni] = fz;

        #pragma unroll 2
        for (int ks = 0; ks < 14; ++ks) {
            const int k0 = ks * 32 + quad * 8;
            bf16x8 a[4], b[4];
            #pragma unroll
            for (int mi = 0; mi < 4; ++mi)
                a[mi] = *(const bf16x8*)&sZ[(mi * 16 + l16) * ZST + k0];
            #pragma unroll
            for (int ni = 0; ni < 4; ++ni)
                b[ni] = *(const bf16x8*)&W3t[(size_t)(nbase + ni * 16 + l16) * ZK + k0];
            #pragma unroll
            for (int mi = 0; mi < 4; ++mi)
                #pragma unroll
                for (int ni = 0; ni < 4; ++ni)
                    acc[mi][ni] = __builtin_amdgcn_mfma_f32_16x16x32_bf16(a[mi], b[ni], acc[mi][ni], 0, 0, 0);
        }
        __syncthreads();
        #pragma unroll
        for (int ni = 0; ni < 4; ++ni) {
            const int n = nbase + ni * 16 + l16;
            const float bias = b3[n];
            #pragma unroll
            for (int mi = 0; mi < 4; ++mi)
                #pragma unroll
                for (int r = 0; r < 4; ++r) {
                    const int row = mi * 16 + quad * 4 + r;
                    sZ[row * ZST + n] = f2bf(fmaxf(acc[mi][ni][r] + bias, 0.f));
                }
        }
        __syncthreads();
    }

    // ---- layer 2: out = t @ W4 + b4, K=256, N=128 (each wave covers 32 cols)
    {
        const int nbase = wave * 32;
        floatx4 acc[4][2];
        #pragma unroll
        for (int mi = 0; mi < 4; ++mi)
            #pragma unroll
            for (int ni = 0; ni < 2; ++ni) acc[mi][ni] = fz;

        #pragma unroll 2
        for (int ks = 0; ks < 8; ++ks) {
            const int k0 = ks * 32 + quad * 8;
            bf16x8 a[4], b[2];
            #pragma unroll
            for (int mi = 0; mi < 4; ++mi)
                a[mi] = *(const bf16x8*)&sZ[(mi * 16 + l16) * ZST + k0];
            #pragma unroll
            for (int ni = 0; ni < 2; ++ni)
                b[ni] = *(const bf16x8*)&W4t[(size_t)(nbase + ni * 16 + l16) * HID + k0];
            #pragma unroll
            for (int mi = 0; mi < 4; ++mi)
                #pragma unroll
                for (int ni = 0; ni < 2; ++ni)
                    acc[mi][ni] = __builtin_amdgcn_mfma_f32_16x16x32_bf16(a[mi], b[ni], acc[mi][ni], 0, 0, 0);
        }
        #pragma unroll
        for (int ni = 0; ni < 2; ++ni) {
            const int feat = nbase + ni * 16 + l16;
            const float bias = b4[feat];
            #pragma unroll
            for (int mi = 0; mi < 4; ++mi)
                #pragma unroll
                for (int r = 0; r < 4; ++r) {
                    const int row = mi * 16 + quad * 4 + r;
                    const int n = n0 + row;
                    if (n < NNODES)
                        out[(size_t)n * NF + feat] = acc[mi][ni][r] + bias;
                }
        }
    }
}

extern "C" void kernel_launch(void* const* d_in, const int* in_sizes, int n_in,
                              void* d_out, int out_size, void* d_ws, size_t ws_size,
                              hipStream_t stream) {
    const float* x   = (const float*)d_in[0];
    const int*   ei  = (const int*)d_in[1];
    const float* ea  = (const float*)d_in[2];
    const float* u   = (const float*)d_in[3];
    const int*   bat = (const int*)d_in[4];
    const float* W1  = (const float*)d_in[5];
    const float* b1  = (const float*)d_in[6];
    const float* W2  = (const float*)d_in[7];
    const float* b2  = (const float*)d_in[8];
    const float* W3  = (const float*)d_in[9];
    const float* b3  = (const float*)d_in[10];
    const float* W4  = (const float*)d_in[11];
    const float* b4  = (const float*)d_in[12];
    float* out = (float*)d_out;

    char* p = (char*)d_ws;
    float* agg = (float*)p;                   p += (size_t)NNODES * HID * 4;
    int* cnt   = (int*)p;                     p += (size_t)NNODES * 4;
    float* inv = (float*)p;                   p += (size_t)NNODES * 4;
    int* excl  = (int*)p;                     p += (size_t)NNODES * 4;
    int* btot  = (int*)p;                     p += 256 * 4;
    int* head  = (int*)p;                     p += (size_t)NNODES * 4;
    int* order = (int*)p;                     p += (size_t)NEDGES * 4;
    int* sdest = (int*)p;                     p += (size_t)NEDGES * 4;
    unsigned short* W1t = (unsigned short*)p; p += (size_t)HID * HID * 2;
    unsigned short* W2t = (unsigned short*)p; p += (size_t)HID * HID * 2;
    unsigned short* W3t = (unsigned short*)p; p += (size_t)ZK * HID * 2;
    unsigned short* W4t = (unsigned short*)p; p += (size_t)HID * NF * 2;

    hipMemsetAsync(agg, 0, (size_t)NNODES * HID * 4, stream);
    hipMemsetAsync(cnt, 0, (size_t)NNODES * 4, stream);

    kconv_t<<<(HID * HID + 255) / 256, 256, 0, stream>>>(W1, W1t, HID, HID);
    kconv_t<<<(HID * HID + 255) / 256, 256, 0, stream>>>(W2, W2t, HID, HID);
    kconv_t<<<(ZK * HID + 255) / 256, 256, 0, stream>>>(W3, W3t, ZK, HID);
    kconv_t<<<(HID * NF + 255) / 256, 256, 0, stream>>>(W4, W4t, HID, NF);

    kcount<<<(NEDGES + 255) / 256, 256, 0, stream>>>(ei, cnt);
    kscan1<<<NSCANB, 256, 0, stream>>>(cnt, excl, btot);
    kscan2<<<1, 256, 0, stream>>>(btot);
    kstart<<<NSCANB, 256, 0, stream>>>(cnt, excl, btot, head, inv);
    kscatter<<<(NEDGES + 255) / 256, 256, 0, stream>>>(ei, head, order, sdest);

    kedge<<<NEDGES / 64, 256, 0, stream>>>(x, ei, ea, order, sdest, W1t, b1, W2t, b2, agg);
    knode<<<(NNODES + 63) / 64, 256, 0, stream>>>(x, agg, inv, u, bat, W3t, b3, W4t, b4, out);
}

// Round 3
// 1048.104 us; speedup vs baseline: 1.2643x; 1.1852x over previous
//
#include <hip/hip_runtime.h>

#define NNODES 50000
#define NEDGES 640000
#define NF 128
#define EF 128
#define UF 64
#define HID 256
#define ZK 448  // NF + HID + UF
#define NSCANB 196  // ceil(NNODES/256)

typedef float floatx4 __attribute__((ext_vector_type(4)));
typedef __bf16 bf16x8 __attribute__((ext_vector_type(8)));

__device__ __forceinline__ unsigned short f2bf(float f) {
    unsigned int u = __float_as_uint(f);
    u += 0x7fffu + ((u >> 16) & 1u);   // RNE
    return (unsigned short)(u >> 16);
}

__device__ __forceinline__ float bf2f(unsigned short h) {
    return __uint_as_float(((unsigned int)h) << 16);
}

// wt[n*K + k] = w[k*N + n]  (K-major bf16 copy for MFMA B-operand loads)
__global__ void kconv_t(const float* __restrict__ w, unsigned short* __restrict__ wt,
                        int K, int N) {
    int i = blockIdx.x * 256 + threadIdx.x;
    if (i >= K * N) return;
    int n = i / K, k = i - n * K;
    wt[i] = f2bf(w[(size_t)k * N + n]);
}

// W3' fold: rows [128,384) of W3 replaced by W23 = W2 @ W3[128:384]; K-major bf16.
__global__ void kfold_w(const float* __restrict__ W2, const float* __restrict__ W3,
                        unsigned short* __restrict__ W3tp) {
    const int k = blockIdx.x;     // 0..447
    const int n = threadIdx.x;    // 0..255
    float v;
    if (k < NF || k >= NF + HID) {
        v = W3[(size_t)k * HID + n];
    } else {
        const int j = k - NF;
        float s = 0.f;
        for (int c = 0; c < HID; ++c)
            s += W2[(size_t)j * HID + c] * W3[(size_t)(NF + c) * HID + n];
        v = s;
    }
    W3tp[(size_t)n * ZK + k] = f2bf(v);
}

// b3' = b3 + b2 @ W3[128:384]
__global__ void kfold_b(const float* __restrict__ b2, const float* __restrict__ b3,
                        const float* __restrict__ W3, float* __restrict__ b3p) {
    const int n = threadIdx.x;
    float s = b3[n];
    for (int c = 0; c < HID; ++c)
        s += b2[c] * W3[(size_t)(NF + c) * HID + n];
    b3p[n] = s;
}

__global__ void kcount(const int* __restrict__ eidx, int* __restrict__ cnt) {
    int i = blockIdx.x * 256 + threadIdx.x;
    if (i < NEDGES) atomicAdd(&cnt[eidx[NEDGES + i]], 1);
}

__global__ void kscan1(const int* __restrict__ cnt, int* __restrict__ excl,
                       int* __restrict__ btot) {
    __shared__ int s[256];
    const int t = threadIdx.x, i = blockIdx.x * 256 + t;
    int v = (i < NNODES) ? cnt[i] : 0;
    s[t] = v;
    __syncthreads();
    for (int off = 1; off < 256; off <<= 1) {
        int add = (t >= off) ? s[t - off] : 0;
        __syncthreads();
        s[t] += add;
        __syncthreads();
    }
    if (i < NNODES) excl[i] = s[t] - v;
    if (t == 255) btot[blockIdx.x] = s[255];
}

__global__ void kscan2(int* __restrict__ btot) {
    __shared__ int s[256];
    const int t = threadIdx.x;
    int v = (t < NSCANB) ? btot[t] : 0;
    s[t] = v;
    __syncthreads();
    for (int off = 1; off < 256; off <<= 1) {
        int add = (t >= off) ? s[t - off] : 0;
        __syncthreads();
        s[t] += add;
        __syncthreads();
    }
    if (t < NSCANB) btot[t] = s[t] - v;
}

__global__ void kstart(const int* __restrict__ cnt, const int* __restrict__ excl,
                       const int* __restrict__ btot, int* __restrict__ head,
                       float* __restrict__ inv) {
    int i = blockIdx.x * 256 + threadIdx.x;
    if (i >= NNODES) return;
    head[i] = excl[i] + btot[blockIdx.x];
    int c = cnt[i];
    inv[i] = 1.0f / (float)(c > 1 ? c : 1);
}

__global__ void kscatter(const int* __restrict__ eidx, int* __restrict__ head,
                         int* __restrict__ order, int* __restrict__ sdest) {
    int e = blockIdx.x * 256 + threadIdx.x;
    if (e < NEDGES) {
        int d = eidx[NEDGES + e];
        int p = atomicAdd(&head[d], 1);
        order[p] = e;
        sdest[p] = d;
    }
}

// 128-col bf16 tile stride: 136*2=272 B, 16B-aligned, rows step 4 banks (free)
#define ESE 136

// P = x @ W1[:128]  (dense, no gather), output bf16 row-major [NNODES,256]
__global__ __launch_bounds__(256)
void kP(const float* __restrict__ x, const unsigned short* __restrict__ W1t,
        unsigned short* __restrict__ Pb) {
    __shared__ unsigned short sX[64 * ESE];
    const int tid = threadIdx.x;
    const int n0 = blockIdx.x * 64;

    for (int i = 0; i < 8; ++i) {
        int lin = (i << 10) + (tid << 2);
        int r = lin >> 7, c = lin & 127;
        int nc = min(n0 + r, NNODES - 1);
        float4 v = *(const float4*)(x + (size_t)nc * NF + c);
        unsigned lo = (unsigned)f2bf(v.x) | ((unsigned)f2bf(v.y) << 16);
        unsigned hi = (unsigned)f2bf(v.z) | ((unsigned)f2bf(v.w) << 16);
        *(uint2*)&sX[r * ESE + c] = make_uint2(lo, hi);
    }
    __syncthreads();

    const int lane = tid & 63, wave = tid >> 6;
    const int l16 = lane & 15, quad = lane >> 4;
    const int nbase = wave * 64;
    const floatx4 fz = {0.f, 0.f, 0.f, 0.f};

    floatx4 acc[4][4];
    #pragma unroll
    for (int mi = 0; mi < 4; ++mi)
        #pragma unroll
        for (int ni = 0; ni < 4; ++ni) acc[mi][ni] = fz;

    #pragma unroll
    for (int ks = 0; ks < 4; ++ks) {
        const int k0 = ks * 32 + quad * 8;
        bf16x8 a[4], b[4];
        #pragma unroll
        for (int mi = 0; mi < 4; ++mi)
            a[mi] = *(const bf16x8*)&sX[(mi * 16 + l16) * ESE + k0];
        #pragma unroll
        for (int ni = 0; ni < 4; ++ni)
            b[ni] = *(const bf16x8*)&W1t[(size_t)(nbase + ni * 16 + l16) * HID + k0];
        #pragma unroll
        for (int mi = 0; mi < 4; ++mi)
            #pragma unroll
            for (int ni = 0; ni < 4; ++ni)
                acc[mi][ni] = __builtin_amdgcn_mfma_f32_16x16x32_bf16(a[mi], b[ni], acc[mi][ni], 0, 0, 0);
    }

    #pragma unroll
    for (int ni = 0; ni < 4; ++ni) {
        const int n = nbase + ni * 16 + l16;
        #pragma unroll
        for (int mi = 0; mi < 4; ++mi)
            #pragma unroll
            for (int r = 0; r < 4; ++r) {
                const int row = mi * 16 + quad * 4 + r;
                const int node = n0 + row;
                if (node < NNODES)
                    Pb[(size_t)node * HID + n] = f2bf(acc[mi][ni][r]);
            }
    }
}

// per sorted-edge tile: Q = ea @ W1[128:], h1r = relu(P[row] + Q + b1),
// merged-run atomic scatter into agg[dest]
__global__ __launch_bounds__(256)
void kscat(const float* __restrict__ ea, const int* __restrict__ eidx,
           const int* __restrict__ order, const int* __restrict__ sdest,
           const unsigned short* __restrict__ Pb,
           const unsigned short* __restrict__ W1t, const float* __restrict__ b1,
           float* __restrict__ agg) {
    __shared__ unsigned short sE[64 * ESE];
    __shared__ int sOrd[64], sRow[64], sCol[64];
    const int tid = threadIdx.x;
    // XCD swizzle: contiguous sorted-edge ranges per XCD -> agg locality in local L2
    const int vb = (blockIdx.x & 7) * 1250 + (blockIdx.x >> 3);
    const int e0 = vb * 64;

    if (tid < 64) {
        int e = order[e0 + tid];
        sOrd[tid] = e;
        sRow[tid] = eidx[e];
        sCol[tid] = sdest[e0 + tid];
    }
    __syncthreads();

    // stage ea -> bf16 LDS, 64 rows x 128 cols
    for (int i = 0; i < 8; ++i) {
        int lin = (i << 10) + (tid << 2);
        int r = lin >> 7, c = lin & 127;
        float4 v = *(const float4*)(ea + (size_t)sOrd[r] * EF + c);
        unsigned lo = (unsigned)f2bf(v.x) | ((unsigned)f2bf(v.y) << 16);
        unsigned hi = (unsigned)f2bf(v.z) | ((unsigned)f2bf(v.w) << 16);
        *(uint2*)&sE[r * ESE + c] = make_uint2(lo, hi);
    }
    __syncthreads();

    const int lane = tid & 63, wave = tid >> 6;
    const int l16 = lane & 15, quad = lane >> 4;
    const int nbase = wave * 64;
    const floatx4 fz = {0.f, 0.f, 0.f, 0.f};

    floatx4 acc[4][4];
    #pragma unroll
    for (int mi = 0; mi < 4; ++mi)
        #pragma unroll
        for (int ni = 0; ni < 4; ++ni) acc[mi][ni] = fz;

    #pragma unroll
    for (int ks = 0; ks < 4; ++ks) {
        const int k0 = ks * 32 + quad * 8;
        bf16x8 a[4], b[4];
        #pragma unroll
        for (int mi = 0; mi < 4; ++mi)
            a[mi] = *(const bf16x8*)&sE[(mi * 16 + l16) * ESE + k0];
        #pragma unroll
        for (int ni = 0; ni < 4; ++ni)
            b[ni] = *(const bf16x8*)&W1t[(size_t)(nbase + ni * 16 + l16) * HID + NF + k0];
        #pragma unroll
        for (int mi = 0; mi < 4; ++mi)
            #pragma unroll
            for (int ni = 0; ni < 4; ++ni)
                acc[mi][ni] = __builtin_amdgcn_mfma_f32_16x16x32_bf16(a[mi], b[ni], acc[mi][ni], 0, 0, 0);
    }

    // epilogue: h1r = relu(Q + P[srow] + b1); merge equal-dest runs (4 consecutive
    // sorted rows per (mi,quad)) then atomic
    #pragma unroll
    for (int ni = 0; ni < 4; ++ni) {
        const int n = nbase + ni * 16 + l16;
        const float bias = b1[n];
        #pragma unroll
        for (int mi = 0; mi < 4; ++mi) {
            const int rbase = mi * 16 + quad * 4;
            float h[4];
            #pragma unroll
            for (int r = 0; r < 4; ++r) {
                const float p = bf2f(Pb[(size_t)sRow[rbase + r] * HID + n]);
                h[r] = fmaxf(acc[mi][ni][r] + p + bias, 0.f);
            }
            int d0 = sCol[rbase];
            float s = h[0];
            #pragma unroll
            for (int r = 1; r < 4; ++r) {
                const int d = sCol[rbase + r];
                if (d == d0) {
                    s += h[r];
                } else {
                    unsafeAtomicAdd(&agg[(size_t)d0 * HID + n], s);
                    d0 = d; s = h[r];
                }
            }
            unsafeAtomicAdd(&agg[(size_t)d0 * HID + n], s);
        }
    }
}

// LDS row stride for 448-wide tiles: 456*2=912 B -> 16B-aligned, banks step 4
#define ZST 456

__global__ __launch_bounds__(256)
void knode(const float* __restrict__ x, const float* __restrict__ agg,
           const float* __restrict__ inv, const float* __restrict__ u,
           const int* __restrict__ batch,
           const unsigned short* __restrict__ W3t, const float* __restrict__ b3,
           const unsigned short* __restrict__ W4t, const float* __restrict__ b4,
           float* __restrict__ out) {
    __shared__ unsigned short sZ[64 * ZST];
    const int tid = threadIdx.x;
    const int n0 = blockIdx.x * 64;

    {
        const int r = tid >> 2, q = tid & 3;
        const int nc = min(n0 + r, NNODES - 1);
        const float invv = inv[nc];
        const int bg = batch[nc];
        for (int j = 0; j < 28; ++j) {
            const int c = q * 112 + (j << 2);
            float4 v;
            if (c < NF) {
                v = *(const float4*)(x + (size_t)nc * NF + c);
            } else if (c < NF + HID) {
                v = *(const float4*)(agg + (size_t)nc * HID + (c - NF));
                v.x *= invv; v.y *= invv; v.z *= invv; v.w *= invv;
            } else {
                v = *(const float4*)(u + (size_t)bg * UF + (c - NF - HID));
            }
            unsigned lo = (unsigned)f2bf(v.x) | ((unsigned)f2bf(v.y) << 16);
            unsigned hi = (unsigned)f2bf(v.z) | ((unsigned)f2bf(v.w) << 16);
            *(uint2*)&sZ[r * ZST + c] = make_uint2(lo, hi);
        }
    }
    __syncthreads();

    const int lane = tid & 63, wave = tid >> 6;
    const int l16 = lane & 15, quad = lane >> 4;
    const floatx4 fz = {0.f, 0.f, 0.f, 0.f};

    // layer 1: t = relu(z @ W3' + b3'), K=448
    {
        const int nbase = wave * 64;
        floatx4 acc[4][4];
        #pragma unroll
        for (int mi = 0; mi < 4; ++mi)
            #pragma unroll
            for (int ni = 0; ni < 4; ++ni) acc[mi][ni] = fz;

        #pragma unroll 2
        for (int ks = 0; ks < 14; ++ks) {
            const int k0 = ks * 32 + quad * 8;
            bf16x8 a[4], b[4];
            #pragma unroll
            for (int mi = 0; mi < 4; ++mi)
                a[mi] = *(const bf16x8*)&sZ[(mi * 16 + l16) * ZST + k0];
            #pragma unroll
            for (int ni = 0; ni < 4; ++ni)
                b[ni] = *(const bf16x8*)&W3t[(size_t)(nbase + ni * 16 + l16) * ZK + k0];
            #pragma unroll
            for (int mi = 0; mi < 4; ++mi)
                #pragma unroll
                for (int ni = 0; ni < 4; ++ni)
                    acc[mi][ni] = __builtin_amdgcn_mfma_f32_16x16x32_bf16(a[mi], b[ni], acc[mi][ni], 0, 0, 0);
        }
        __syncthreads();
        #pragma unroll
        for (int ni = 0; ni < 4; ++ni) {
            const int n = nbase + ni * 16 + l16;
            const float bias = b3[n];
            #pragma unroll
            for (int mi = 0; mi < 4; ++mi)
                #pragma unroll
                for (int r = 0; r < 4; ++r) {
                    const int row = mi * 16 + quad * 4 + r;
                    sZ[row * ZST + n] = f2bf(fmaxf(acc[mi][ni][r] + bias, 0.f));
                }
        }
        __syncthreads();
    }

    // layer 2: out = t @ W4 + b4, K=256, N=128
    {
        const int nbase = wave * 32;
        floatx4 acc[4][2];
        #pragma unroll
        for (int mi = 0; mi < 4; ++mi)
            #pragma unroll
            for (int ni = 0; ni < 2; ++ni) acc[mi][ni] = fz;

        #pragma unroll 2
        for (int ks = 0; ks < 8; ++ks) {
            const int k0 = ks * 32 + quad * 8;
            bf16x8 a[4], b[2];
            #pragma unroll
            for (int mi = 0; mi < 4; ++mi)
                a[mi] = *(const bf16x8*)&sZ[(mi * 16 + l16) * ZST + k0];
            #pragma unroll
            for (int ni = 0; ni < 2; ++ni)
                b[ni] = *(const bf16x8*)&W4t[(size_t)(nbase + ni * 16 + l16) * HID + k0];
            #pragma unroll
            for (int mi = 0; mi < 4; ++mi)
                #pragma unroll
                for (int ni = 0; ni < 2; ++ni)
                    acc[mi][ni] = __builtin_amdgcn_mfma_f32_16x16x32_bf16(a[mi], b[ni], acc[mi][ni], 0, 0, 0);
        }
        #pragma unroll
        for (int ni = 0; ni < 2; ++ni) {
            const int feat = nbase + ni * 16 + l16;
            const float bias = b4[feat];
            #pragma unroll
            for (int mi = 0; mi < 4; ++mi)
                #pragma unroll
                for (int r = 0; r < 4; ++r) {
                    const int row = mi * 16 + quad * 4 + r;
                    const int n = n0 + row;
                    if (n < NNODES)
                        out[(size_t)n * NF + feat] = acc[mi][ni][r] + bias;
                }
        }
    }
}

extern "C" void kernel_launch(void* const* d_in, const int* in_sizes, int n_in,
                              void* d_out, int out_size, void* d_ws, size_t ws_size,
                              hipStream_t stream) {
    const float* x   = (const float*)d_in[0];
    const int*   ei  = (const int*)d_in[1];
    const float* ea  = (const float*)d_in[2];
    const float* u   = (const float*)d_in[3];
    const int*   bat = (const int*)d_in[4];
    const float* W1  = (const float*)d_in[5];
    const float* b1  = (const float*)d_in[6];
    const float* W2  = (const float*)d_in[7];
    const float* b2  = (const float*)d_in[8];
    const float* W3  = (const float*)d_in[9];
    const float* b3  = (const float*)d_in[10];
    const float* W4  = (const float*)d_in[11];
    const float* b4  = (const float*)d_in[12];
    float* out = (float*)d_out;

    char* p = (char*)d_ws;
    float* agg = (float*)p;                   p += (size_t)NNODES * HID * 4;
    int* cnt   = (int*)p;                     p += (size_t)NNODES * 4;
    float* inv = (float*)p;                   p += (size_t)NNODES * 4;
    int* excl  = (int*)p;                     p += (size_t)NNODES * 4;
    int* btot  = (int*)p;                     p += 256 * 4;
    int* head  = (int*)p;                     p += (size_t)NNODES * 4;
    int* order = (int*)p;                     p += (size_t)NEDGES * 4;
    int* sdest = (int*)p;                     p += (size_t)NEDGES * 4;
    unsigned short* Pb  = (unsigned short*)p; p += (size_t)NNODES * HID * 2;
    unsigned short* W1t = (unsigned short*)p; p += (size_t)HID * HID * 2;
    unsigned short* W3tp= (unsigned short*)p; p += (size_t)ZK * HID * 2;
    unsigned short* W4t = (unsigned short*)p; p += (size_t)HID * NF * 2;
    float* b3p = (float*)p;                   p += (size_t)HID * 4;

    hipMemsetAsync(agg, 0, (size_t)NNODES * HID * 4, stream);
    hipMemsetAsync(cnt, 0, (size_t)NNODES * 4, stream);

    kconv_t<<<(HID * HID + 255) / 256, 256, 0, stream>>>(W1, W1t, HID, HID);
    kconv_t<<<(HID * NF + 255) / 256, 256, 0, stream>>>(W4, W4t, HID, NF);
    kfold_w<<<ZK, 256, 0, stream>>>(W2, W3, W3tp);
    kfold_b<<<1, 256, 0, stream>>>(b2, b3, W3, b3p);

    kcount<<<(NEDGES + 255) / 256, 256, 0, stream>>>(ei, cnt);
    kscan1<<<NSCANB, 256, 0, stream>>>(cnt, excl, btot);
    kscan2<<<1, 256, 0, stream>>>(btot);
    kstart<<<NSCANB, 256, 0, stream>>>(cnt, excl, btot, head, inv);
    kscatter<<<(NEDGES + 255) / 256, 256, 0, stream>>>(ei, head, order, sdest);

    kP<<<(NNODES + 63) / 64, 256, 0, stream>>>(x, W1t, Pb);
    kscat<<<NEDGES / 64, 256, 0, stream>>>(ea, ei, order, sdest, Pb, W1t, b1, agg);
    knode<<<(NNODES + 63) / 64, 256, 0, stream>>>(x, agg, inv, u, bat, W3tp, b3p, W4t, b4, out);
}